// Round 13
// baseline (59.690 us; speedup 1.0000x reference)
//
#include <hip/hip_runtime.h>
#include <hip/hip_fp16.h>
#include <math.h>

#define BB 4
#define CC 256
#define HH 100
#define WW 100
#define HWP (HH * WW)
#define NPIX (BB * HWP)

#define CGN 4                    // channel groups
#define CHB 64                   // channels per group
#define ROWB (CHB * 2)           // 128 B per (position, group)

#define XT_BYTES ((size_t)NPIX * CC * 2)       // 20.48 MB, [b][cg][h][w][64] fp16
#define FEAT_BYTES ((size_t)CGN * NPIX * 4)    // 0.64 MB

#define NP_BLOCKS (BB * HH * 2)                // 800 transpose blocks (half-ch)

#define TILE 8
#define HALO 16
#define TPD 13
#define TPI (TPD * TPD)                        // 169
#define NBLK (BB * CGN * TPI)                  // 2704 = 8 * 338

#define KGSPLIT 7                              // taps < this use the LDS halo

// ROCm 7.2 hip_fp16.h lacks __hmax2 — emit packed f16 ops directly.
static __device__ inline uint pk_max_f16(uint a, uint b) {
    uint r;
    asm("v_pk_max_f16 %0, %1, %2" : "=v"(r) : "v"(a), "v"(b));
    return r;
}
// d = a * broadcast(w.lo)   (VOP3P op_sel broadcast of src1 low half)
static __device__ inline uint pk_mul_bl(uint a, uint w) {
    uint r;
    asm("v_pk_mul_f16 %0, %1, %2 op_sel:[0,0] op_sel_hi:[1,0]"
        : "=v"(r) : "v"(a), "v"(w));
    return r;
}
// d = a * broadcast(w.lo) + c
static __device__ inline uint pk_fma_bl(uint a, uint w, uint c) {
    uint r;
    asm("v_pk_fma_f16 %0, %1, %2, %3 op_sel:[0,0,0] op_sel_hi:[1,0,1]"
        : "=v"(r) : "v"(a), "v"(w), "v"(c));
    return r;
}
// d = a * broadcast(w.hi) + c
static __device__ inline uint pk_fma_bh(uint a, uint w, uint c) {
    uint r;
    asm("v_pk_fma_f16 %0, %1, %2, %3 op_sel:[0,1,0] op_sel_hi:[1,1,1]"
        : "=v"(r) : "v"(a), "v"(w), "v"(c));
    return r;
}

// ---------------------------------------------------------------------------
// Prep: 800 blocks, each transposes ONE (b,h,half) = 128 channels x 100 cols.
// 26 KB LDS -> ~6 blocks/CU capacity, 3.1 resident rounds (R12: 400 blocks at
// 51.6 KB = 1.56/CU, tail-imbalanced ~2x BW floor).
// x[b,c,h,w] f32 -> xTg[b][cg][h][w][64] fp16.
// ---------------------------------------------------------------------------
__global__ __launch_bounds__(256) void prep_kernel(
    const float* __restrict__ x, ushort* __restrict__ xT) {
    __shared__ uint tileT[WW][65];   // [w][c2loc], 100*65*4 = 26 KB
    int bid = blockIdx.x;
    int b = bid / (HH * 2);
    int rem = bid - b * (HH * 2);
    int h = rem >> 1;
    int half = rem & 1;              // which 128-channel half
    const float* src = x + (size_t)b * CC * HWP + (size_t)(half * 128) * HWP +
                       (size_t)h * WW;

    // read: 64 channel-pairs x 25 float4 columns
    for (int idx = threadIdx.x; idx < 64 * 25; idx += 256) {
        int c2 = idx / 25;
        int w4 = idx - c2 * 25;
        const float* p0 = src + (size_t)(2 * c2) * HWP + w4 * 4;
        float4 va = *reinterpret_cast<const float4*>(p0);
        float4 vb = *reinterpret_cast<const float4*>(p0 + HWP);
        __half2 h0 = __floats2half2_rn(va.x, vb.x);
        __half2 h1 = __floats2half2_rn(va.y, vb.y);
        __half2 h2 = __floats2half2_rn(va.z, vb.z);
        __half2 h3 = __floats2half2_rn(va.w, vb.w);
        tileT[w4 * 4 + 0][c2] = *reinterpret_cast<uint*>(&h0);
        tileT[w4 * 4 + 1][c2] = *reinterpret_cast<uint*>(&h1);
        tileT[w4 * 4 + 2][c2] = *reinterpret_cast<uint*>(&h2);
        tileT[w4 * 4 + 3][c2] = *reinterpret_cast<uint*>(&h3);
    }
    __syncthreads();

    // write: 100 w x 32 uint2 slots (4 ch each)
    uint2* dstu = reinterpret_cast<uint2*>(xT);
    for (int idx = threadIdx.x; idx < WW * 32; idx += 256) {
        int w = idx >> 5;
        int s = idx & 31;                    // local 4-ch slot
        int cg = half * 2 + (s >> 4);
        int c4in = s & 15;
        size_t o = ((size_t)((b * CGN + cg) * HH + h) * WW + w) * 16 + c4in;
        dstu[o] = make_uint2(tileT[w][2 * s], tileT[w][2 * s + 1]);
    }
}

// ---------------------------------------------------------------------------
// Deform v6: block = 512 thr, 8x8 pixel tile, ONE 64-ch group.
// Taps 0..6 via 32KB LDS halo, taps 7..8 via global/L2 (loads pre-issued
// before the LDS taps so VMEM flies under DS work). Weights applied with
// op_sel-broadcast v_pk_fma_f16 (no unpack VALU). Geometry computed
// in-kernel into LDS. SQ_LDS_BANK_CONFLICT==0 in all captures -> swizzle
// retained but known-neutral; b128's 8-phase minimum is the DS cost.
// ---------------------------------------------------------------------------
__global__ __launch_bounds__(512, 6) void deform_tiled6_kernel(
    const char* __restrict__ xTg, const float* __restrict__ off,
    const float* __restrict__ w0, float* __restrict__ feat) {
    __shared__ uint4 halo4[HALO * HALO * 8];   // 32 KiB
    __shared__ int4 geomL[TILE * TILE * 9];    // 9 KiB, idx = px*9+k

    int lb = (blockIdx.x & 7) * (NBLK / 8) + (blockIdx.x >> 3);
    int pl = lb / TPI;                         // 0..15 = (b,cg) plane
    int tile = lb - pl * TPI;
    int b = pl >> 2, cg = pl & 3;
    int tyi = tile / TPD;
    int ty = tyi * TILE;
    int tx = (tile - tyi * TPD) * TILE;
    int sy = min(max(ty - 4, 0), HH - HALO);
    int sx = min(max(tx - 4, 0), WW - HALO);
    int plane = (b * CGN + cg) * HH;

    // ---- stage halo (bank-swizzled) ----
    const char* hbase = xTg + ((size_t)(plane + sy) * WW + sx) * ROWB;
#pragma unroll
    for (int it = 0; it < 4; ++it) {
        int i = it * 512 + threadIdx.x;        // 0..2047
        int strip = i >> 7;
        int within = i & 127;
        uint4 v = *reinterpret_cast<const uint4*>(
            hbase + (size_t)strip * (WW * ROWB) + ((size_t)within << 4));
        int pos = (strip << 4) + (within >> 3);
        int c = within & 7;
        halo4[(pos << 3) + (c ^ (pos & 7))] = v;
    }
    // ---- compute geometry tile in-kernel ----
    {
        const float* offb = off + (size_t)b * 18 * HWP;
        for (int i = threadIdx.x; i < 9 * 64; i += 512) {
            int k = i >> 6;
            int px = i & 63;
            int r = px >> 3, c = px & 7;
            int h2 = min(ty + r, HH - 1);
            int w2 = min(tx + c, WW - 1);
            int hw = h2 * WW + w2;
            float dy = offb[(size_t)(2 * k) * HWP + hw];
            float dx = offb[(size_t)(2 * k + 1) * HWP + hw];
            int kh = k / 3 - 1;
            int kw = k - (k / 3) * 3 - 1;
            float py = (float)(h2 + kh) + dy;
            float px_ = (float)(w2 + kw) + dx;
            float y0f = floorf(py), x0f = floorf(px_);
            float wy = py - y0f, wx = px_ - x0f;
            int y0 = (int)y0f, x0 = (int)x0f;
            int y1 = y0 + 1, x1 = x0 + 1;
            bool vy0 = (y0 >= 0) && (y0 < HH);
            bool vy1 = (y1 >= 0) && (y1 < HH);
            bool vx0 = (x0 >= 0) && (x0 < WW);
            bool vx1 = (x1 >= 0) && (x1 < WW);
            int yc0 = min(max(y0, 0), HH - 1);
            int yc1 = min(max(y1, 0), HH - 1);
            int xc0 = min(max(x0, 0), WW - 1);
            int xc1 = min(max(x1, 0), WW - 1);
            float w00 = (1.f - wy) * (1.f - wx) * (float)(vy0 && vx0);
            float w01 = (1.f - wy) * wx * (float)(vy0 && vx1);
            float w10 = wy * (1.f - wx) * (float)(vy1 && vx0);
            float w11 = wy * wx * (float)(vy1 && vx1);
            int packed = yc0 | (yc1 << 8) | (xc0 << 16) | (xc1 << 24);
            __half2 hw01 = __floats2half2_rn(w00, w01);
            __half2 hw23 = __floats2half2_rn(w10, w11);
            geomL[px * 9 + k] =
                make_int4(packed, *reinterpret_cast<int*>(&hw01),
                          *reinterpret_cast<int*>(&hw23), 0);
        }
    }
    __syncthreads();

    int lane = threadIdx.x & 63;
    int wid = threadIdx.x >> 6;                // tile row 0..7
    int sub = lane >> 3;                       // tile col 0..7
    int cl = lane & 7;                         // 16B channel slot
    int h = ty + wid, wc = tx + sub;
    bool pvalid = (h < HH) && (wc < WW);
    int pi = wid * 8 + sub;
    int lo = cl << 4;

    uint m0 = 0xFC00FC00u, m1 = m0, m2 = m0, m3 = m0;

    // ---- pre-issue global taps 7,8 ----
    int4 rec7 = geomL[pi * 9 + 7];
    int4 rec8 = geomL[pi * 9 + 8];
    uint4 g7[4], g8[4];
#define GLOAD(dst, rec)                                                      \
    {                                                                        \
        int pk_ = rec.x;                                                     \
        int yc0_ = pk_ & 255, yc1_ = (pk_ >> 8) & 255;                       \
        int xc0_ = (pk_ >> 16) & 255, xc1_ = (int)((uint)pk_ >> 24);         \
        dst[0] = *reinterpret_cast<const uint4*>(                            \
            xTg + ((size_t)(plane + yc0_) * WW + xc0_) * ROWB + lo);         \
        dst[1] = *reinterpret_cast<const uint4*>(                            \
            xTg + ((size_t)(plane + yc0_) * WW + xc1_) * ROWB + lo);         \
        dst[2] = *reinterpret_cast<const uint4*>(                            \
            xTg + ((size_t)(plane + yc1_) * WW + xc0_) * ROWB + lo);         \
        dst[3] = *reinterpret_cast<const uint4*>(                            \
            xTg + ((size_t)(plane + yc1_) * WW + xc1_) * ROWB + lo);         \
    }
    GLOAD(g7, rec7)
    GLOAD(g8, rec8)
#undef GLOAD

#define BLEND4(u00, u01, u10, u11, wa, wb)                                   \
    {                                                                        \
        uint acc;                                                            \
        acc = pk_mul_bl(u00.x, wa); acc = pk_fma_bh(u01.x, wa, acc);         \
        acc = pk_fma_bl(u10.x, wb, acc); acc = pk_fma_bh(u11.x, wb, acc);    \
        m0 = pk_max_f16(m0, acc);                                            \
        acc = pk_mul_bl(u00.y, wa); acc = pk_fma_bh(u01.y, wa, acc);         \
        acc = pk_fma_bl(u10.y, wb, acc); acc = pk_fma_bh(u11.y, wb, acc);    \
        m1 = pk_max_f16(m1, acc);                                            \
        acc = pk_mul_bl(u00.z, wa); acc = pk_fma_bh(u01.z, wa, acc);         \
        acc = pk_fma_bl(u10.z, wb, acc); acc = pk_fma_bh(u11.z, wb, acc);    \
        m2 = pk_max_f16(m2, acc);                                            \
        acc = pk_mul_bl(u00.w, wa); acc = pk_fma_bh(u01.w, wa, acc);         \
        acc = pk_fma_bl(u10.w, wb, acc); acc = pk_fma_bh(u11.w, wb, acc);    \
        m3 = pk_max_f16(m3, acc);                                            \
    }

    // ---- LDS taps 0..6 ----
#pragma unroll
    for (int k = 0; k < KGSPLIT; ++k) {
        int4 rec = geomL[pi * 9 + k];
        int packed = rec.x;
        int yc0 = packed & 255, yc1 = (packed >> 8) & 255;
        int xc0 = (packed >> 16) & 255, xc1 = (int)((uint)packed >> 24);
        int ry0 = yc0 - sy, ry1 = yc1 - sy;
        int cx0 = xc0 - sx, cx1 = xc1 - sx;
        bool inh = ((uint)ry0 < (uint)HALO) & ((uint)ry1 < (uint)HALO) &
                   ((uint)cx0 < (uint)HALO) & ((uint)cx1 < (uint)HALO);
        uint4 u00, u01, u10, u11;
        if (__all(inh)) {
            int p00 = (ry0 << 4) + cx0, p01 = (ry0 << 4) + cx1;
            int p10 = (ry1 << 4) + cx0, p11 = (ry1 << 4) + cx1;
            u00 = halo4[(p00 << 3) + (cl ^ (cx0 & 7))];
            u01 = halo4[(p01 << 3) + (cl ^ (cx1 & 7))];
            u10 = halo4[(p10 << 3) + (cl ^ (cx0 & 7))];
            u11 = halo4[(p11 << 3) + (cl ^ (cx1 & 7))];
        } else {
            u00 = *reinterpret_cast<const uint4*>(
                xTg + ((size_t)(plane + yc0) * WW + xc0) * ROWB + lo);
            u01 = *reinterpret_cast<const uint4*>(
                xTg + ((size_t)(plane + yc0) * WW + xc1) * ROWB + lo);
            u10 = *reinterpret_cast<const uint4*>(
                xTg + ((size_t)(plane + yc1) * WW + xc0) * ROWB + lo);
            u11 = *reinterpret_cast<const uint4*>(
                xTg + ((size_t)(plane + yc1) * WW + xc1) * ROWB + lo);
        }
        uint wa = (uint)rec.y, wb = (uint)rec.z;
        BLEND4(u00, u01, u10, u11, wa, wb)
    }

    // ---- global taps 7,8 ----
    {
        uint wa = (uint)rec7.y, wb = (uint)rec7.z;
        BLEND4(g7[0], g7[1], g7[2], g7[3], wa, wb)
        wa = (uint)rec8.y; wb = (uint)rec8.z;
        BLEND4(g8[0], g8[1], g8[2], g8[3], wa, wb)
    }
#undef BLEND4

    // dot with w0: channels cg*64 + cl*8 .. +7
    const float4* wv = reinterpret_cast<const float4*>(w0) + (cg * 16 + cl * 2);
    float4 wq0 = wv[0], wq1 = wv[1];
    float2 f0 = __half22float2(*reinterpret_cast<__half2*>(&m0));
    float2 f1 = __half22float2(*reinterpret_cast<__half2*>(&m1));
    float2 f2 = __half22float2(*reinterpret_cast<__half2*>(&m2));
    float2 f3 = __half22float2(*reinterpret_cast<__half2*>(&m3));
    float part = f0.x * wq0.x + f0.y * wq0.y + f1.x * wq0.z + f1.y * wq0.w +
                 f2.x * wq1.x + f2.y * wq1.y + f3.x * wq1.z + f3.y * wq1.w;
#pragma unroll
    for (int d = 4; d > 0; d >>= 1) part += __shfl_down(part, d, 8);
    if (cl == 0 && pvalid)
        feat[(size_t)cg * NPIX + b * HWP + h * WW + wc] = part;
}

// ---------------------------------------------------------------------------
// Combine: out = sigmoid(sum_cg feat + bias)
// ---------------------------------------------------------------------------
__global__ __launch_bounds__(256) void combine_kernel(
    const float* __restrict__ feat, const float* __restrict__ b0,
    float* __restrict__ out) {
    int i = blockIdx.x * 256 + threadIdx.x;
    if (i < NPIX) {
        float z = feat[i] + feat[NPIX + i] + feat[2 * NPIX + i] +
                  feat[3 * NPIX + i] + b0[0];
        out[i] = 1.f / (1.f + expf(-z));
    }
}

// ---------------------------------------------------------------------------
// Fallback: one block (128 threads) per pixel, f32 path, no workspace needed.
// ---------------------------------------------------------------------------
__global__ __launch_bounds__(128) void deform_fallback_kernel(
    const float* __restrict__ x, const float* __restrict__ off,
    const float* __restrict__ w0, const float* __restrict__ b0,
    float* __restrict__ out) {
    int p = blockIdx.x;
    int b = p / HWP;
    int hw = p - b * HWP;
    int h = hw / WW;
    int w = hw - h * WW;
    int tid = threadIdx.x;

    const float* offp = off + (size_t)b * 18 * HWP + hw;
    const float* xb = x + (size_t)b * CC * HWP + (size_t)(2 * tid) * HWP;

    float m0 = -INFINITY, m1 = -INFINITY;

#pragma unroll
    for (int k = 0; k < 9; ++k) {
        int kh = k / 3 - 1;
        int kw = k - (k / 3) * 3 - 1;
        float dy = offp[(size_t)(2 * k) * HWP];
        float dx = offp[(size_t)(2 * k + 1) * HWP];
        float py = (float)(h + kh) + dy;
        float px = (float)(w + kw) + dx;
        float y0f = floorf(py), x0f = floorf(px);
        float wy = py - y0f, wx = px - x0f;
        int y0 = (int)y0f, x0 = (int)x0f;
        int y1 = y0 + 1, x1 = x0 + 1;
        bool vy0 = (y0 >= 0) && (y0 < HH);
        bool vy1 = (y1 >= 0) && (y1 < HH);
        bool vx0 = (x0 >= 0) && (x0 < WW);
        bool vx1 = (x1 >= 0) && (x1 < WW);
        int yc0 = min(max(y0, 0), HH - 1);
        int yc1 = min(max(y1, 0), HH - 1);
        int xc0 = min(max(x0, 0), WW - 1);
        int xc1 = min(max(x1, 0), WW - 1);
        float w00 = (1.f - wy) * (1.f - wx) * (float)(vy0 && vx0);
        float w01 = (1.f - wy) * wx * (float)(vy0 && vx1);
        float w10 = wy * (1.f - wx) * (float)(vy1 && vx0);
        float w11 = wy * wx * (float)(vy1 && vx1);

        int o00 = yc0 * WW + xc0, o01 = yc0 * WW + xc1;
        int o10 = yc1 * WW + xc0, o11 = yc1 * WW + xc1;
        float s0 = xb[o00] * w00 + xb[o01] * w01 + xb[o10] * w10 + xb[o11] * w11;
        float s1 = xb[o00 + HWP] * w00 + xb[o01 + HWP] * w01 +
                   xb[o10 + HWP] * w10 + xb[o11 + HWP] * w11;
        m0 = fmaxf(m0, s0);
        m1 = fmaxf(m1, s1);
    }

    float2 wv = reinterpret_cast<const float2*>(w0)[tid];
    float partial = m0 * wv.x + m1 * wv.y;
#pragma unroll
    for (int d = 32; d > 0; d >>= 1) partial += __shfl_down(partial, d, 64);

    __shared__ float red[2];
    if ((tid & 63) == 0) red[tid >> 6] = partial;
    __syncthreads();
    if (tid == 0) {
        float z = red[0] + red[1] + b0[0];
        out[p] = 1.f / (1.f + expf(-z));
    }
}

extern "C" void kernel_launch(void* const* d_in, const int* in_sizes, int n_in,
                              void* d_out, int out_size, void* d_ws, size_t ws_size,
                              hipStream_t stream) {
    const float* x   = (const float*)d_in[0];
    const float* off = (const float*)d_in[1];
    const float* w0  = (const float*)d_in[2];
    const float* b0  = (const float*)d_in[3];
    float* out = (float*)d_out;

    if (ws_size >= XT_BYTES + FEAT_BYTES) {
        char* xT = (char*)d_ws;
        float* feat = (float*)((char*)d_ws + XT_BYTES);
        prep_kernel<<<NP_BLOCKS, 256, 0, stream>>>(x, (ushort*)xT);
        deform_tiled6_kernel<<<NBLK, 512, 0, stream>>>(xT, off, w0, feat);
        combine_kernel<<<(NPIX + 255) / 256, 256, 0, stream>>>(feat, b0, out);
    } else {
        deform_fallback_kernel<<<NPIX, 128, 0, stream>>>(x, off, w0, b0, out);
    }
}

// Round 14
// 41.781 us; speedup vs baseline: 1.4287x; 1.4287x over previous
//
#include <hip/hip_runtime.h>
#include <hip/hip_fp16.h>
#include <math.h>

#define BB 4
#define CC 256
#define HH 100
#define WW 100
#define HWP (HH * WW)
#define NPIX (BB * HWP)

#define CGN 4                    // channel groups
#define CHB 64                   // channels per group
#define ROWB (CHB * 2)           // 128 B per (position, group)

#define XT_BYTES ((size_t)NPIX * CC * 2)       // 20.48 MB, [b][cg][h][w][64] fp16
#define FEAT_BYTES ((size_t)CGN * NPIX * 4)    // 0.64 MB

#define NP_BLOCKS (BB * HH * 2)                // 800 transpose blocks (half-ch)

#define TILE 8
#define HALO 16
#define TPD 13
#define TPI (TPD * TPD)                        // 169
#define NBLK (BB * CGN * TPI)                  // 2704 = 8 * 338

#define KGSPLIT 6                              // taps < this use the LDS halo

// ROCm 7.2 hip_fp16.h lacks __hmax2 — emit packed f16 ops directly.
static __device__ inline uint pk_max_f16(uint a, uint b) {
    uint r;
    asm("v_pk_max_f16 %0, %1, %2" : "=v"(r) : "v"(a), "v"(b));
    return r;
}
// d = a * broadcast(w.lo)
static __device__ inline uint pk_mul_bl(uint a, uint w) {
    uint r;
    asm("v_pk_mul_f16 %0, %1, %2 op_sel:[0,0] op_sel_hi:[1,0]"
        : "=v"(r) : "v"(a), "v"(w));
    return r;
}
// d = a * broadcast(w.lo) + c
static __device__ inline uint pk_fma_bl(uint a, uint w, uint c) {
    uint r;
    asm("v_pk_fma_f16 %0, %1, %2, %3 op_sel:[0,0,0] op_sel_hi:[1,0,1]"
        : "=v"(r) : "v"(a), "v"(w), "v"(c));
    return r;
}
// d = a * broadcast(w.hi) + c
static __device__ inline uint pk_fma_bh(uint a, uint w, uint c) {
    uint r;
    asm("v_pk_fma_f16 %0, %1, %2, %3 op_sel:[0,1,0] op_sel_hi:[1,1,1]"
        : "=v"(r) : "v"(a), "v"(w), "v"(c));
    return r;
}

// ---------------------------------------------------------------------------
// Prep: 800 blocks, each transposes ONE (b,h,half) = 128 channels x 100 cols.
// 26 KB LDS -> ~6 blocks/CU capacity. x[b,c,h,w] f32 -> xTg[b][cg][h][w][64].
// ---------------------------------------------------------------------------
__global__ __launch_bounds__(256) void prep_kernel(
    const float* __restrict__ x, ushort* __restrict__ xT) {
    __shared__ uint tileT[WW][65];   // [w][c2loc], 26 KB
    int bid = blockIdx.x;
    int b = bid / (HH * 2);
    int rem = bid - b * (HH * 2);
    int h = rem >> 1;
    int half = rem & 1;
    const float* src = x + (size_t)b * CC * HWP + (size_t)(half * 128) * HWP +
                       (size_t)h * WW;

    for (int idx = threadIdx.x; idx < 64 * 25; idx += 256) {
        int c2 = idx / 25;
        int w4 = idx - c2 * 25;
        const float* p0 = src + (size_t)(2 * c2) * HWP + w4 * 4;
        float4 va = *reinterpret_cast<const float4*>(p0);
        float4 vb = *reinterpret_cast<const float4*>(p0 + HWP);
        __half2 h0 = __floats2half2_rn(va.x, vb.x);
        __half2 h1 = __floats2half2_rn(va.y, vb.y);
        __half2 h2 = __floats2half2_rn(va.z, vb.z);
        __half2 h3 = __floats2half2_rn(va.w, vb.w);
        tileT[w4 * 4 + 0][c2] = *reinterpret_cast<uint*>(&h0);
        tileT[w4 * 4 + 1][c2] = *reinterpret_cast<uint*>(&h1);
        tileT[w4 * 4 + 2][c2] = *reinterpret_cast<uint*>(&h2);
        tileT[w4 * 4 + 3][c2] = *reinterpret_cast<uint*>(&h3);
    }
    __syncthreads();

    uint2* dstu = reinterpret_cast<uint2*>(xT);
    for (int idx = threadIdx.x; idx < WW * 32; idx += 256) {
        int w = idx >> 5;
        int s = idx & 31;
        int cg = half * 2 + (s >> 4);
        int c4in = s & 15;
        size_t o = ((size_t)((b * CGN + cg) * HH + h) * WW + w) * 16 + c4in;
        dstu[o] = make_uint2(tileT[w][2 * s], tileT[w][2 * s + 1]);
    }
}

// ---------------------------------------------------------------------------
// Deform v7 (= v5 structure + op_sel FMA): block = 512 thr, 8x8 pixel tile,
// ONE 64-ch group. Taps 0..5 via LDS halo, 6..8 inline global (L2-resident).
// R13 lesson: pre-issued staging arrays spilled to scratch (40 MB WRITE_SIZE,
// 51us) -> NO manual staging; inline loads only. Weights via op_sel-broadcast
// v_pk_fma_f16 (no unpack VALU). Geometry computed in-kernel into LDS.
// ---------------------------------------------------------------------------
__global__ __launch_bounds__(512, 6) void deform_tiled7_kernel(
    const char* __restrict__ xTg, const float* __restrict__ off,
    const float* __restrict__ w0, float* __restrict__ feat) {
    __shared__ uint4 halo4[HALO * HALO * 8];   // 32 KiB
    __shared__ int4 geomL[TILE * TILE * 9];    // 9 KiB, idx = px*9+k

    int lb = (blockIdx.x & 7) * (NBLK / 8) + (blockIdx.x >> 3);
    int pl = lb / TPI;                         // 0..15 = (b,cg) plane
    int tile = lb - pl * TPI;
    int b = pl >> 2, cg = pl & 3;
    int tyi = tile / TPD;
    int ty = tyi * TILE;
    int tx = (tile - tyi * TPD) * TILE;
    int sy = min(max(ty - 4, 0), HH - HALO);
    int sx = min(max(tx - 4, 0), WW - HALO);
    int plane = (b * CGN + cg) * HH;

    // ---- stage halo (bank-swizzled) ----
    const char* hbase = xTg + ((size_t)(plane + sy) * WW + sx) * ROWB;
#pragma unroll
    for (int it = 0; it < 4; ++it) {
        int i = it * 512 + threadIdx.x;        // 0..2047
        int strip = i >> 7;
        int within = i & 127;
        uint4 v = *reinterpret_cast<const uint4*>(
            hbase + (size_t)strip * (WW * ROWB) + ((size_t)within << 4));
        int pos = (strip << 4) + (within >> 3);
        int c = within & 7;
        halo4[(pos << 3) + (c ^ (pos & 7))] = v;
    }
    // ---- compute geometry tile in-kernel ----
    {
        const float* offb = off + (size_t)b * 18 * HWP;
        for (int i = threadIdx.x; i < 9 * 64; i += 512) {
            int k = i >> 6;
            int px = i & 63;
            int r = px >> 3, c = px & 7;
            int h2 = min(ty + r, HH - 1);
            int w2 = min(tx + c, WW - 1);
            int hw = h2 * WW + w2;
            float dy = offb[(size_t)(2 * k) * HWP + hw];
            float dx = offb[(size_t)(2 * k + 1) * HWP + hw];
            int kh = k / 3 - 1;
            int kw = k - (k / 3) * 3 - 1;
            float py = (float)(h2 + kh) + dy;
            float px_ = (float)(w2 + kw) + dx;
            float y0f = floorf(py), x0f = floorf(px_);
            float wy = py - y0f, wx = px_ - x0f;
            int y0 = (int)y0f, x0 = (int)x0f;
            int y1 = y0 + 1, x1 = x0 + 1;
            bool vy0 = (y0 >= 0) && (y0 < HH);
            bool vy1 = (y1 >= 0) && (y1 < HH);
            bool vx0 = (x0 >= 0) && (x0 < WW);
            bool vx1 = (x1 >= 0) && (x1 < WW);
            int yc0 = min(max(y0, 0), HH - 1);
            int yc1 = min(max(y1, 0), HH - 1);
            int xc0 = min(max(x0, 0), WW - 1);
            int xc1 = min(max(x1, 0), WW - 1);
            float w00 = (1.f - wy) * (1.f - wx) * (float)(vy0 && vx0);
            float w01 = (1.f - wy) * wx * (float)(vy0 && vx1);
            float w10 = wy * (1.f - wx) * (float)(vy1 && vx0);
            float w11 = wy * wx * (float)(vy1 && vx1);
            int packed = yc0 | (yc1 << 8) | (xc0 << 16) | (xc1 << 24);
            __half2 hw01 = __floats2half2_rn(w00, w01);
            __half2 hw23 = __floats2half2_rn(w10, w11);
            geomL[px * 9 + k] =
                make_int4(packed, *reinterpret_cast<int*>(&hw01),
                          *reinterpret_cast<int*>(&hw23), 0);
        }
    }
    __syncthreads();

    int lane = threadIdx.x & 63;
    int wid = threadIdx.x >> 6;                // tile row 0..7
    int sub = lane >> 3;                       // tile col 0..7
    int cl = lane & 7;                         // 16B channel slot
    int h = ty + wid, wc = tx + sub;
    bool pvalid = (h < HH) && (wc < WW);
    int pi = wid * 8 + sub;
    int lo = cl << 4;

    uint m0 = 0xFC00FC00u, m1 = m0, m2 = m0, m3 = m0;

#define BLEND4(u00, u01, u10, u11, wa, wb)                                   \
    {                                                                        \
        uint acc;                                                            \
        acc = pk_mul_bl(u00.x, wa); acc = pk_fma_bh(u01.x, wa, acc);         \
        acc = pk_fma_bl(u10.x, wb, acc); acc = pk_fma_bh(u11.x, wb, acc);    \
        m0 = pk_max_f16(m0, acc);                                            \
        acc = pk_mul_bl(u00.y, wa); acc = pk_fma_bh(u01.y, wa, acc);         \
        acc = pk_fma_bl(u10.y, wb, acc); acc = pk_fma_bh(u11.y, wb, acc);    \
        m1 = pk_max_f16(m1, acc);                                            \
        acc = pk_mul_bl(u00.z, wa); acc = pk_fma_bh(u01.z, wa, acc);         \
        acc = pk_fma_bl(u10.z, wb, acc); acc = pk_fma_bh(u11.z, wb, acc);    \
        m2 = pk_max_f16(m2, acc);                                            \
        acc = pk_mul_bl(u00.w, wa); acc = pk_fma_bh(u01.w, wa, acc);         \
        acc = pk_fma_bl(u10.w, wb, acc); acc = pk_fma_bh(u11.w, wb, acc);    \
        m3 = pk_max_f16(m3, acc);                                            \
    }

#pragma unroll
    for (int k = 0; k < 9; ++k) {
        int4 rec = geomL[pi * 9 + k];
        int packed = rec.x;
        int yc0 = packed & 255, yc1 = (packed >> 8) & 255;
        int xc0 = (packed >> 16) & 255, xc1 = (int)((uint)packed >> 24);
        uint4 u00, u01, u10, u11;
        bool useLds = false;
        if (k < KGSPLIT) {
            int ry0 = yc0 - sy, ry1 = yc1 - sy;
            int cx0 = xc0 - sx, cx1 = xc1 - sx;
            bool inh = ((uint)ry0 < (uint)HALO) & ((uint)ry1 < (uint)HALO) &
                       ((uint)cx0 < (uint)HALO) & ((uint)cx1 < (uint)HALO);
            useLds = __all(inh);
            if (useLds) {
                int p00 = (ry0 << 4) + cx0, p01 = (ry0 << 4) + cx1;
                int p10 = (ry1 << 4) + cx0, p11 = (ry1 << 4) + cx1;
                u00 = halo4[(p00 << 3) + (cl ^ (cx0 & 7))];
                u01 = halo4[(p01 << 3) + (cl ^ (cx1 & 7))];
                u10 = halo4[(p10 << 3) + (cl ^ (cx0 & 7))];
                u11 = halo4[(p11 << 3) + (cl ^ (cx1 & 7))];
            }
        }
        if (!useLds) {
            u00 = *reinterpret_cast<const uint4*>(
                xTg + ((size_t)(plane + yc0) * WW + xc0) * ROWB + lo);
            u01 = *reinterpret_cast<const uint4*>(
                xTg + ((size_t)(plane + yc0) * WW + xc1) * ROWB + lo);
            u10 = *reinterpret_cast<const uint4*>(
                xTg + ((size_t)(plane + yc1) * WW + xc0) * ROWB + lo);
            u11 = *reinterpret_cast<const uint4*>(
                xTg + ((size_t)(plane + yc1) * WW + xc1) * ROWB + lo);
        }
        uint wa = (uint)rec.y, wb = (uint)rec.z;
        BLEND4(u00, u01, u10, u11, wa, wb)
    }
#undef BLEND4

    // dot with w0: channels cg*64 + cl*8 .. +7
    const float4* wv = reinterpret_cast<const float4*>(w0) + (cg * 16 + cl * 2);
    float4 wq0 = wv[0], wq1 = wv[1];
    float2 f0 = __half22float2(*reinterpret_cast<__half2*>(&m0));
    float2 f1 = __half22float2(*reinterpret_cast<__half2*>(&m1));
    float2 f2 = __half22float2(*reinterpret_cast<__half2*>(&m2));
    float2 f3 = __half22float2(*reinterpret_cast<__half2*>(&m3));
    float part = f0.x * wq0.x + f0.y * wq0.y + f1.x * wq0.z + f1.y * wq0.w +
                 f2.x * wq1.x + f2.y * wq1.y + f3.x * wq1.z + f3.y * wq1.w;
#pragma unroll
    for (int d = 4; d > 0; d >>= 1) part += __shfl_down(part, d, 8);
    if (cl == 0 && pvalid)
        feat[(size_t)cg * NPIX + b * HWP + h * WW + wc] = part;
}

// ---------------------------------------------------------------------------
// Combine: out = sigmoid(sum_cg feat + bias)
// ---------------------------------------------------------------------------
__global__ __launch_bounds__(256) void combine_kernel(
    const float* __restrict__ feat, const float* __restrict__ b0,
    float* __restrict__ out) {
    int i = blockIdx.x * 256 + threadIdx.x;
    if (i < NPIX) {
        float z = feat[i] + feat[NPIX + i] + feat[2 * NPIX + i] +
                  feat[3 * NPIX + i] + b0[0];
        out[i] = 1.f / (1.f + expf(-z));
    }
}

// ---------------------------------------------------------------------------
// Fallback: one block (128 threads) per pixel, f32 path, no workspace needed.
// ---------------------------------------------------------------------------
__global__ __launch_bounds__(128) void deform_fallback_kernel(
    const float* __restrict__ x, const float* __restrict__ off,
    const float* __restrict__ w0, const float* __restrict__ b0,
    float* __restrict__ out) {
    int p = blockIdx.x;
    int b = p / HWP;
    int hw = p - b * HWP;
    int h = hw / WW;
    int w = hw - h * WW;
    int tid = threadIdx.x;

    const float* offp = off + (size_t)b * 18 * HWP + hw;
    const float* xb = x + (size_t)b * CC * HWP + (size_t)(2 * tid) * HWP;

    float m0 = -INFINITY, m1 = -INFINITY;

#pragma unroll
    for (int k = 0; k < 9; ++k) {
        int kh = k / 3 - 1;
        int kw = k - (k / 3) * 3 - 1;
        float dy = offp[(size_t)(2 * k) * HWP];
        float dx = offp[(size_t)(2 * k + 1) * HWP];
        float py = (float)(h + kh) + dy;
        float px = (float)(w + kw) + dx;
        float y0f = floorf(py), x0f = floorf(px);
        float wy = py - y0f, wx = px - x0f;
        int y0 = (int)y0f, x0 = (int)x0f;
        int y1 = y0 + 1, x1 = x0 + 1;
        bool vy0 = (y0 >= 0) && (y0 < HH);
        bool vy1 = (y1 >= 0) && (y1 < HH);
        bool vx0 = (x0 >= 0) && (x0 < WW);
        bool vx1 = (x1 >= 0) && (x1 < WW);
        int yc0 = min(max(y0, 0), HH - 1);
        int yc1 = min(max(y1, 0), HH - 1);
        int xc0 = min(max(x0, 0), WW - 1);
        int xc1 = min(max(x1, 0), WW - 1);
        float w00 = (1.f - wy) * (1.f - wx) * (float)(vy0 && vx0);
        float w01 = (1.f - wy) * wx * (float)(vy0 && vx1);
        float w10 = wy * (1.f - wx) * (float)(vy1 && vx0);
        float w11 = wy * wx * (float)(vy1 && vx1);

        int o00 = yc0 * WW + xc0, o01 = yc0 * WW + xc1;
        int o10 = yc1 * WW + xc0, o11 = yc1 * WW + xc1;
        float s0 = xb[o00] * w00 + xb[o01] * w01 + xb[o10] * w10 + xb[o11] * w11;
        float s1 = xb[o00 + HWP] * w00 + xb[o01 + HWP] * w01 +
                   xb[o10 + HWP] * w10 + xb[o11 + HWP] * w11;
        m0 = fmaxf(m0, s0);
        m1 = fmaxf(m1, s1);
    }

    float2 wv = reinterpret_cast<const float2*>(w0)[tid];
    float partial = m0 * wv.x + m1 * wv.y;
#pragma unroll
    for (int d = 32; d > 0; d >>= 1) partial += __shfl_down(partial, d, 64);

    __shared__ float red[2];
    if ((tid & 63) == 0) red[tid >> 6] = partial;
    __syncthreads();
    if (tid == 0) {
        float z = red[0] + red[1] + b0[0];
        out[p] = 1.f / (1.f + expf(-z));
    }
}

extern "C" void kernel_launch(void* const* d_in, const int* in_sizes, int n_in,
                              void* d_out, int out_size, void* d_ws, size_t ws_size,
                              hipStream_t stream) {
    const float* x   = (const float*)d_in[0];
    const float* off = (const float*)d_in[1];
    const float* w0  = (const float*)d_in[2];
    const float* b0  = (const float*)d_in[3];
    float* out = (float*)d_out;

    if (ws_size >= XT_BYTES + FEAT_BYTES) {
        char* xT = (char*)d_ws;
        float* feat = (float*)((char*)d_ws + XT_BYTES);
        prep_kernel<<<NP_BLOCKS, 256, 0, stream>>>(x, (ushort*)xT);
        deform_tiled7_kernel<<<NBLK, 512, 0, stream>>>(xT, off, w0, feat);
        combine_kernel<<<(NPIX + 255) / 256, 256, 0, stream>>>(feat, b0, out);
    } else {
        deform_fallback_kernel<<<NPIX, 128, 0, stream>>>(x, off, w0, b0, out);
    }
}

// Round 15
// 41.617 us; speedup vs baseline: 1.4343x; 1.0039x over previous
//
#include <hip/hip_runtime.h>
#include <hip/hip_fp16.h>
#include <math.h>

#define BB 4
#define CC 256
#define HH 100
#define WW 100
#define HWP (HH * WW)
#define NPIX (BB * HWP)

#define CGN 4                    // channel groups
#define CHB 64                   // channels per group
#define ROWB (CHB * 2)           // 128 B per (position, group)

#define XT_BYTES ((size_t)NPIX * CC * 2)       // 20.48 MB, [b][cg][h][w][64] fp16
#define FEAT_BYTES ((size_t)CGN * NPIX * 4)    // 0.64 MB

#define NP_BLOCKS (BB * HH * 2)                // 800 transpose blocks (half-ch)

#define TILE 8
#define HALO 16
#define TPD 13
#define TPI (TPD * TPD)                        // 169
#define NBLK (BB * CGN * TPI)                  // 2704 = 8 * 338

#define KGSPLIT 7                              // taps < this use the LDS halo
// R14 pipe balance: KGSPLIT=6 -> DS ~10us, VMEM ~17us (global is long pole).
// KGSPLIT=7 -> DS ~12us, VMEM ~11us (balanced). R13's KGSPLIT=7 result was
// invalid (scratch spill from staged loads); this is the clean inline test.

// ROCm 7.2 hip_fp16.h lacks __hmax2 — emit packed f16 ops directly.
static __device__ inline uint pk_max_f16(uint a, uint b) {
    uint r;
    asm("v_pk_max_f16 %0, %1, %2" : "=v"(r) : "v"(a), "v"(b));
    return r;
}
// d = a * broadcast(w.lo)
static __device__ inline uint pk_mul_bl(uint a, uint w) {
    uint r;
    asm("v_pk_mul_f16 %0, %1, %2 op_sel:[0,0] op_sel_hi:[1,0]"
        : "=v"(r) : "v"(a), "v"(w));
    return r;
}
// d = a * broadcast(w.lo) + c
static __device__ inline uint pk_fma_bl(uint a, uint w, uint c) {
    uint r;
    asm("v_pk_fma_f16 %0, %1, %2, %3 op_sel:[0,0,0] op_sel_hi:[1,0,1]"
        : "=v"(r) : "v"(a), "v"(w), "v"(c));
    return r;
}
// d = a * broadcast(w.hi) + c
static __device__ inline uint pk_fma_bh(uint a, uint w, uint c) {
    uint r;
    asm("v_pk_fma_f16 %0, %1, %2, %3 op_sel:[0,1,0] op_sel_hi:[1,1,1]"
        : "=v"(r) : "v"(a), "v"(w), "v"(c));
    return r;
}

// ---------------------------------------------------------------------------
// Prep: 800 blocks, each transposes ONE (b,h,half) = 128 channels x 100 cols.
// 26 KB LDS -> ~6 blocks/CU capacity. x[b,c,h,w] f32 -> xTg[b][cg][h][w][64].
// ---------------------------------------------------------------------------
__global__ __launch_bounds__(256) void prep_kernel(
    const float* __restrict__ x, ushort* __restrict__ xT) {
    __shared__ uint tileT[WW][65];   // [w][c2loc], 26 KB
    int bid = blockIdx.x;
    int b = bid / (HH * 2);
    int rem = bid - b * (HH * 2);
    int h = rem >> 1;
    int half = rem & 1;
    const float* src = x + (size_t)b * CC * HWP + (size_t)(half * 128) * HWP +
                       (size_t)h * WW;

    for (int idx = threadIdx.x; idx < 64 * 25; idx += 256) {
        int c2 = idx / 25;
        int w4 = idx - c2 * 25;
        const float* p0 = src + (size_t)(2 * c2) * HWP + w4 * 4;
        float4 va = *reinterpret_cast<const float4*>(p0);
        float4 vb = *reinterpret_cast<const float4*>(p0 + HWP);
        __half2 h0 = __floats2half2_rn(va.x, vb.x);
        __half2 h1 = __floats2half2_rn(va.y, vb.y);
        __half2 h2 = __floats2half2_rn(va.z, vb.z);
        __half2 h3 = __floats2half2_rn(va.w, vb.w);
        tileT[w4 * 4 + 0][c2] = *reinterpret_cast<uint*>(&h0);
        tileT[w4 * 4 + 1][c2] = *reinterpret_cast<uint*>(&h1);
        tileT[w4 * 4 + 2][c2] = *reinterpret_cast<uint*>(&h2);
        tileT[w4 * 4 + 3][c2] = *reinterpret_cast<uint*>(&h3);
    }
    __syncthreads();

    uint2* dstu = reinterpret_cast<uint2*>(xT);
    for (int idx = threadIdx.x; idx < WW * 32; idx += 256) {
        int w = idx >> 5;
        int s = idx & 31;
        int cg = half * 2 + (s >> 4);
        int c4in = s & 15;
        size_t o = ((size_t)((b * CGN + cg) * HH + h) * WW + w) * 16 + c4in;
        dstu[o] = make_uint2(tileT[w][2 * s], tileT[w][2 * s + 1]);
    }
}

// ---------------------------------------------------------------------------
// Deform v8 (= v7 with KGSPLIT=7): block = 512 thr, 8x8 pixel tile, ONE
// 64-ch group. Taps 0..6 via LDS halo, 7..8 inline global (L2-resident).
// NO manual load staging (R13: spills -> 40MB scratch traffic). Weights via
// op_sel-broadcast v_pk_fma_f16. Geometry computed in-kernel into LDS.
// ---------------------------------------------------------------------------
__global__ __launch_bounds__(512, 6) void deform_tiled8_kernel(
    const char* __restrict__ xTg, const float* __restrict__ off,
    const float* __restrict__ w0, float* __restrict__ feat) {
    __shared__ uint4 halo4[HALO * HALO * 8];   // 32 KiB
    __shared__ int4 geomL[TILE * TILE * 9];    // 9 KiB, idx = px*9+k

    int lb = (blockIdx.x & 7) * (NBLK / 8) + (blockIdx.x >> 3);
    int pl = lb / TPI;                         // 0..15 = (b,cg) plane
    int tile = lb - pl * TPI;
    int b = pl >> 2, cg = pl & 3;
    int tyi = tile / TPD;
    int ty = tyi * TILE;
    int tx = (tile - tyi * TPD) * TILE;
    int sy = min(max(ty - 4, 0), HH - HALO);
    int sx = min(max(tx - 4, 0), WW - HALO);
    int plane = (b * CGN + cg) * HH;

    // ---- stage halo (bank-swizzled) ----
    const char* hbase = xTg + ((size_t)(plane + sy) * WW + sx) * ROWB;
#pragma unroll
    for (int it = 0; it < 4; ++it) {
        int i = it * 512 + threadIdx.x;        // 0..2047
        int strip = i >> 7;
        int within = i & 127;
        uint4 v = *reinterpret_cast<const uint4*>(
            hbase + (size_t)strip * (WW * ROWB) + ((size_t)within << 4));
        int pos = (strip << 4) + (within >> 3);
        int c = within & 7;
        halo4[(pos << 3) + (c ^ (pos & 7))] = v;
    }
    // ---- compute geometry tile in-kernel ----
    {
        const float* offb = off + (size_t)b * 18 * HWP;
        for (int i = threadIdx.x; i < 9 * 64; i += 512) {
            int k = i >> 6;
            int px = i & 63;
            int r = px >> 3, c = px & 7;
            int h2 = min(ty + r, HH - 1);
            int w2 = min(tx + c, WW - 1);
            int hw = h2 * WW + w2;
            float dy = offb[(size_t)(2 * k) * HWP + hw];
            float dx = offb[(size_t)(2 * k + 1) * HWP + hw];
            int kh = k / 3 - 1;
            int kw = k - (k / 3) * 3 - 1;
            float py = (float)(h2 + kh) + dy;
            float px_ = (float)(w2 + kw) + dx;
            float y0f = floorf(py), x0f = floorf(px_);
            float wy = py - y0f, wx = px_ - x0f;
            int y0 = (int)y0f, x0 = (int)x0f;
            int y1 = y0 + 1, x1 = x0 + 1;
            bool vy0 = (y0 >= 0) && (y0 < HH);
            bool vy1 = (y1 >= 0) && (y1 < HH);
            bool vx0 = (x0 >= 0) && (x0 < WW);
            bool vx1 = (x1 >= 0) && (x1 < WW);
            int yc0 = min(max(y0, 0), HH - 1);
            int yc1 = min(max(y1, 0), HH - 1);
            int xc0 = min(max(x0, 0), WW - 1);
            int xc1 = min(max(x1, 0), WW - 1);
            float w00 = (1.f - wy) * (1.f - wx) * (float)(vy0 && vx0);
            float w01 = (1.f - wy) * wx * (float)(vy0 && vx1);
            float w10 = wy * (1.f - wx) * (float)(vy1 && vx0);
            float w11 = wy * wx * (float)(vy1 && vx1);
            int packed = yc0 | (yc1 << 8) | (xc0 << 16) | (xc1 << 24);
            __half2 hw01 = __floats2half2_rn(w00, w01);
            __half2 hw23 = __floats2half2_rn(w10, w11);
            geomL[px * 9 + k] =
                make_int4(packed, *reinterpret_cast<int*>(&hw01),
                          *reinterpret_cast<int*>(&hw23), 0);
        }
    }
    __syncthreads();

    int lane = threadIdx.x & 63;
    int wid = threadIdx.x >> 6;                // tile row 0..7
    int sub = lane >> 3;                       // tile col 0..7
    int cl = lane & 7;                         // 16B channel slot
    int h = ty + wid, wc = tx + sub;
    bool pvalid = (h < HH) && (wc < WW);
    int pi = wid * 8 + sub;
    int lo = cl << 4;

    uint m0 = 0xFC00FC00u, m1 = m0, m2 = m0, m3 = m0;

#define BLEND4(u00, u01, u10, u11, wa, wb)                                   \
    {                                                                        \
        uint acc;                                                            \
        acc = pk_mul_bl(u00.x, wa); acc = pk_fma_bh(u01.x, wa, acc);         \
        acc = pk_fma_bl(u10.x, wb, acc); acc = pk_fma_bh(u11.x, wb, acc);    \
        m0 = pk_max_f16(m0, acc);                                            \
        acc = pk_mul_bl(u00.y, wa); acc = pk_fma_bh(u01.y, wa, acc);         \
        acc = pk_fma_bl(u10.y, wb, acc); acc = pk_fma_bh(u11.y, wb, acc);    \
        m1 = pk_max_f16(m1, acc);                                            \
        acc = pk_mul_bl(u00.z, wa); acc = pk_fma_bh(u01.z, wa, acc);         \
        acc = pk_fma_bl(u10.z, wb, acc); acc = pk_fma_bh(u11.z, wb, acc);    \
        m2 = pk_max_f16(m2, acc);                                            \
        acc = pk_mul_bl(u00.w, wa); acc = pk_fma_bh(u01.w, wa, acc);         \
        acc = pk_fma_bl(u10.w, wb, acc); acc = pk_fma_bh(u11.w, wb, acc);    \
        m3 = pk_max_f16(m3, acc);                                            \
    }

#pragma unroll
    for (int k = 0; k < 9; ++k) {
        int4 rec = geomL[pi * 9 + k];
        int packed = rec.x;
        int yc0 = packed & 255, yc1 = (packed >> 8) & 255;
        int xc0 = (packed >> 16) & 255, xc1 = (int)((uint)packed >> 24);
        uint4 u00, u01, u10, u11;
        bool useLds = false;
        if (k < KGSPLIT) {
            int ry0 = yc0 - sy, ry1 = yc1 - sy;
            int cx0 = xc0 - sx, cx1 = xc1 - sx;
            bool inh = ((uint)ry0 < (uint)HALO) & ((uint)ry1 < (uint)HALO) &
                       ((uint)cx0 < (uint)HALO) & ((uint)cx1 < (uint)HALO);
            useLds = __all(inh);
            if (useLds) {
                int p00 = (ry0 << 4) + cx0, p01 = (ry0 << 4) + cx1;
                int p10 = (ry1 << 4) + cx0, p11 = (ry1 << 4) + cx1;
                u00 = halo4[(p00 << 3) + (cl ^ (cx0 & 7))];
                u01 = halo4[(p01 << 3) + (cl ^ (cx1 & 7))];
                u10 = halo4[(p10 << 3) + (cl ^ (cx0 & 7))];
                u11 = halo4[(p11 << 3) + (cl ^ (cx1 & 7))];
            }
        }
        if (!useLds) {
            u00 = *reinterpret_cast<const uint4*>(
                xTg + ((size_t)(plane + yc0) * WW + xc0) * ROWB + lo);
            u01 = *reinterpret_cast<const uint4*>(
                xTg + ((size_t)(plane + yc0) * WW + xc1) * ROWB + lo);
            u10 = *reinterpret_cast<const uint4*>(
                xTg + ((size_t)(plane + yc1) * WW + xc0) * ROWB + lo);
            u11 = *reinterpret_cast<const uint4*>(
                xTg + ((size_t)(plane + yc1) * WW + xc1) * ROWB + lo);
        }
        uint wa = (uint)rec.y, wb = (uint)rec.z;
        BLEND4(u00, u01, u10, u11, wa, wb)
    }
#undef BLEND4

    // dot with w0: channels cg*64 + cl*8 .. +7
    const float4* wv = reinterpret_cast<const float4*>(w0) + (cg * 16 + cl * 2);
    float4 wq0 = wv[0], wq1 = wv[1];
    float2 f0 = __half22float2(*reinterpret_cast<__half2*>(&m0));
    float2 f1 = __half22float2(*reinterpret_cast<__half2*>(&m1));
    float2 f2 = __half22float2(*reinterpret_cast<__half2*>(&m2));
    float2 f3 = __half22float2(*reinterpret_cast<__half2*>(&m3));
    float part = f0.x * wq0.x + f0.y * wq0.y + f1.x * wq0.z + f1.y * wq0.w +
                 f2.x * wq1.x + f2.y * wq1.y + f3.x * wq1.z + f3.y * wq1.w;
#pragma unroll
    for (int d = 4; d > 0; d >>= 1) part += __shfl_down(part, d, 8);
    if (cl == 0 && pvalid)
        feat[(size_t)cg * NPIX + b * HWP + h * WW + wc] = part;
}

// ---------------------------------------------------------------------------
// Combine: out = sigmoid(sum_cg feat + bias)
// ---------------------------------------------------------------------------
__global__ __launch_bounds__(256) void combine_kernel(
    const float* __restrict__ feat, const float* __restrict__ b0,
    float* __restrict__ out) {
    int i = blockIdx.x * 256 + threadIdx.x;
    if (i < NPIX) {
        float z = feat[i] + feat[NPIX + i] + feat[2 * NPIX + i] +
                  feat[3 * NPIX + i] + b0[0];
        out[i] = 1.f / (1.f + expf(-z));
    }
}

// ---------------------------------------------------------------------------
// Fallback: one block (128 threads) per pixel, f32 path, no workspace needed.
// ---------------------------------------------------------------------------
__global__ __launch_bounds__(128) void deform_fallback_kernel(
    const float* __restrict__ x, const float* __restrict__ off,
    const float* __restrict__ w0, const float* __restrict__ b0,
    float* __restrict__ out) {
    int p = blockIdx.x;
    int b = p / HWP;
    int hw = p - b * HWP;
    int h = hw / WW;
    int w = hw - h * WW;
    int tid = threadIdx.x;

    const float* offp = off + (size_t)b * 18 * HWP + hw;
    const float* xb = x + (size_t)b * CC * HWP + (size_t)(2 * tid) * HWP;

    float m0 = -INFINITY, m1 = -INFINITY;

#pragma unroll
    for (int k = 0; k < 9; ++k) {
        int kh = k / 3 - 1;
        int kw = k - (k / 3) * 3 - 1;
        float dy = offp[(size_t)(2 * k) * HWP];
        float dx = offp[(size_t)(2 * k + 1) * HWP];
        float py = (float)(h + kh) + dy;
        float px = (float)(w + kw) + dx;
        float y0f = floorf(py), x0f = floorf(px);
        float wy = py - y0f, wx = px - x0f;
        int y0 = (int)y0f, x0 = (int)x0f;
        int y1 = y0 + 1, x1 = x0 + 1;
        bool vy0 = (y0 >= 0) && (y0 < HH);
        bool vy1 = (y1 >= 0) && (y1 < HH);
        bool vx0 = (x0 >= 0) && (x0 < WW);
        bool vx1 = (x1 >= 0) && (x1 < WW);
        int yc0 = min(max(y0, 0), HH - 1);
        int yc1 = min(max(y1, 0), HH - 1);
        int xc0 = min(max(x0, 0), WW - 1);
        int xc1 = min(max(x1, 0), WW - 1);
        float w00 = (1.f - wy) * (1.f - wx) * (float)(vy0 && vx0);
        float w01 = (1.f - wy) * wx * (float)(vy0 && vx1);
        float w10 = wy * (1.f - wx) * (float)(vy1 && vx0);
        float w11 = wy * wx * (float)(vy1 && vx1);

        int o00 = yc0 * WW + xc0, o01 = yc0 * WW + xc1;
        int o10 = yc1 * WW + xc0, o11 = yc1 * WW + xc1;
        float s0 = xb[o00] * w00 + xb[o01] * w01 + xb[o10] * w10 + xb[o11] * w11;
        float s1 = xb[o00 + HWP] * w00 + xb[o01 + HWP] * w01 +
                   xb[o10 + HWP] * w10 + xb[o11 + HWP] * w11;
        m0 = fmaxf(m0, s0);
        m1 = fmaxf(m1, s1);
    }

    float2 wv = reinterpret_cast<const float2*>(w0)[tid];
    float partial = m0 * wv.x + m1 * wv.y;
#pragma unroll
    for (int d = 32; d > 0; d >>= 1) partial += __shfl_down(partial, d, 64);

    __shared__ float red[2];
    if ((tid & 63) == 0) red[tid >> 6] = partial;
    __syncthreads();
    if (tid == 0) {
        float z = red[0] + red[1] + b0[0];
        out[p] = 1.f / (1.f + expf(-z));
    }
}

extern "C" void kernel_launch(void* const* d_in, const int* in_sizes, int n_in,
                              void* d_out, int out_size, void* d_ws, size_t ws_size,
                              hipStream_t stream) {
    const float* x   = (const float*)d_in[0];
    const float* off = (const float*)d_in[1];
    const float* w0  = (const float*)d_in[2];
    const float* b0  = (const float*)d_in[3];
    float* out = (float*)d_out;

    if (ws_size >= XT_BYTES + FEAT_BYTES) {
        char* xT = (char*)d_ws;
        float* feat = (float*)((char*)d_ws + XT_BYTES);
        prep_kernel<<<NP_BLOCKS, 256, 0, stream>>>(x, (ushort*)xT);
        deform_tiled8_kernel<<<NBLK, 512, 0, stream>>>(xT, off, w0, feat);
        combine_kernel<<<(NPIX + 255) / 256, 256, 0, stream>>>(feat, b0, out);
    } else {
        deform_fallback_kernel<<<NPIX, 128, 0, stream>>>(x, off, w0, b0, out);
    }
}